// Round 9
// baseline (505.473 us; speedup 1.0000x reference)
//
#include <hip/hip_runtime.h>
#include <hip/hip_cooperative_groups.h>
#include <math.h>

namespace cg = cooperative_groups;

#define KHALF 5
#define MAXF 256  // max fire count per batch (Lp1 <= 128 here)

// ---------------- standalone kernels (multi-launch path, R7-proven) ----------------

__global__ void k_weff(const float* __restrict__ conv_w, const float* __restrict__ conv_b,
                       const float* __restrict__ proj_w, const float* __restrict__ proj_b,
                       float* __restrict__ w_eff, float* __restrict__ b_eff,
                       int KD, int C) {
    int gid = blockIdx.x * blockDim.x + threadIdx.x;
    int wave = gid >> 6;
    int lane = gid & 63;
    if (wave > KD) return;
    float s = 0.f;
    if (wave < KD) {
        const float* row = conv_w + (size_t)wave * C;
        for (int c = lane * 4; c < C; c += 256) {
            float4 v = *reinterpret_cast<const float4*>(row + c);
            float4 w = *reinterpret_cast<const float4*>(proj_w + c);
            s += v.x * w.x + v.y * w.y + v.z * w.z + v.w * w.w;
        }
    } else {
        for (int c = lane; c < C; c += 64) s += conv_b[c] * proj_w[c];
    }
#pragma unroll
    for (int off = 32; off > 0; off >>= 1) s += __shfl_down(s, off, 64);
    if (lane == 0) {
        if (wave < KD) w_eff[wave] = s;
        else           b_eff[0] = s + proj_b[0];
    }
}

__global__ __launch_bounds__(256) void k_qdot(const float* __restrict__ eouts,
                                              const float* __restrict__ w_eff,
                                              float* __restrict__ q, int BT) {
    __shared__ float tile[64 * 132];
    __shared__ float part[64 * 49];
    const int u0 = blockIdx.x * 64;
    const int lane = threadIdx.x & 63;
    const int s = __builtin_amdgcn_readfirstlane(threadIdx.x >> 6);
    float acc[11];
#pragma unroll
    for (int k = 0; k < 11; ++k) acc[k] = 0.f;
    for (int c = 0; c < 4; ++c) {
        __syncthreads();
#pragma unroll
        for (int it = 0; it < 8; ++it) {
            int idx = it * 256 + threadIdx.x;
            int r = idx >> 5, j4 = idx & 31;
            float4 v = *reinterpret_cast<const float4*>(
                eouts + (size_t)(u0 + r) * 512 + c * 128 + j4 * 4);
            *reinterpret_cast<float4*>(&tile[r * 132 + j4 * 4]) = v;
        }
        __syncthreads();
#pragma unroll
        for (int j4 = 0; j4 < 8; ++j4) {
            float4 av = *reinterpret_cast<const float4*>(&tile[lane * 132 + s * 32 + j4 * 4]);
            int dg = c * 128 + s * 32 + j4 * 4;
#pragma unroll
            for (int k = 0; k < 11; ++k) {
                float4 wv = *reinterpret_cast<const float4*>(w_eff + k * 512 + dg);
                acc[k] += av.x * wv.x + av.y * wv.y + av.z * wv.z + av.w * wv.w;
            }
        }
    }
#pragma unroll
    for (int k = 0; k < 11; ++k) part[lane * 49 + s * 12 + k] = acc[k];
    __syncthreads();
    if (threadIdx.x < 64) {
        int r = threadIdx.x;
        const float* p = &part[r * 49];
        float o[12];
#pragma unroll
        for (int k = 0; k < 11; ++k)
            o[k] = (p[k] + p[12 + k]) + (p[24 + k] + p[36 + k]);
        o[11] = 0.f;
        float4* dst = reinterpret_cast<float4*>(q + (size_t)(u0 + r) * 12);
        dst[0] = make_float4(o[0], o[1], o[2], o[3]);
        dst[1] = make_float4(o[4], o[5], o[6], o[7]);
        dst[2] = make_float4(o[8], o[9], o[10], o[11]);
    }
}

__global__ __launch_bounds__(256) void k_sigpart(const float* __restrict__ q,
                                                 const float* __restrict__ b_eff,
                                                 float* __restrict__ alpha,
                                                 float* __restrict__ partials,
                                                 int T, int tcb) {
    __shared__ float qs[266 * 12];
    __shared__ float psm[4];
    int bx = blockIdx.x;
    int b = bx / tcb, tc = bx % tcb;
    int t0 = tc * 256;
    const float* qb = q + (size_t)b * T * 12;
    const int base = (t0 - 5) * 12;
    const int lim = T * 12;
    for (int i = threadIdx.x; i < 266 * 12; i += 256) {
        int gi = base + i;
        qs[i] = (gi >= 0 && gi < lim) ? qb[gi] : 0.f;
    }
    __syncthreads();
    int t = t0 + threadIdx.x;
    float sacc = b_eff[0];
#pragma unroll
    for (int k = 0; k < 11; ++k) sacc += qs[(threadIdx.x + k) * 12 + k];
    float al = 1.f / (1.f + expf(-sacc));
    alpha[(size_t)b * T + t] = al;
    float s = al;
    int lane = threadIdx.x & 63;
    int w = threadIdx.x >> 6;
#pragma unroll
    for (int off = 32; off > 0; off >>= 1) s += __shfl_down(s, off, 64);
    if (lane == 0) psm[w] = s;
    __syncthreads();
    if (threadIdx.x == 0) {
        float tot = 0.f;
        for (int i = 0; i < 4; ++i) tot += psm[i];
        partials[bx] = tot;
    }
}

__global__ void k_alpha(const float* __restrict__ eouts,
                        const float* __restrict__ w_eff,
                        const float* __restrict__ b_eff,
                        float* __restrict__ alpha,
                        int B, int T, int D) {
    const int W = 2 * KHALF + 1;
    int gid = blockIdx.x * blockDim.x + threadIdx.x;
    int wave = gid >> 6;
    int lane = gid & 63;
    if (wave >= B * T) return;
    int b = wave / T;
    int t = wave - b * T;
    int WD = W * D;
    int t0 = t - KHALF;
    float s = 0.f;
    if (t0 >= 0 && t0 + W <= T) {
        const float* base = eouts + ((size_t)b * T + t0) * D;
        for (int j = lane * 4; j < WD; j += 256) {
            float4 v = *reinterpret_cast<const float4*>(base + j);
            float4 w = *reinterpret_cast<const float4*>(w_eff + j);
            s += v.x * w.x + v.y * w.y + v.z * w.z + v.w * w.w;
        }
    } else {
        const float* base = eouts + (size_t)b * T * D;
        for (int j = lane; j < WD; j += 64) {
            int tt = t0 + j / D;
            if (tt >= 0 && tt < T) {
                int d = j - (j / D) * D;
                s += base[(size_t)tt * D + d] * w_eff[j];
            }
        }
    }
#pragma unroll
    for (int off = 32; off > 0; off >>= 1) s += __shfl_down(s, off, 64);
    if (lane == 0) {
        float logit = s + b_eff[0];
        alpha[(size_t)b * T + t] = 1.f / (1.f + expf(-logit));
    }
}

__global__ void k_chain(const float* __restrict__ alpha_in,
                        int use_part,
                        const float* __restrict__ partials, int npart,
                        const int* __restrict__ elens,
                        const int* __restrict__ ylens,
                        float* __restrict__ alpha_sum,
                        int* __restrict__ n_fired,
                        int* __restrict__ fire_t,
                        float* __restrict__ fire_a1,
                        float* __restrict__ fire_a2,
                        int T, int Lp1) {
    extern __shared__ float an[];
    __shared__ float sm[16];
    __shared__ float stot;
    int b = blockIdx.x;
    const float* row = alpha_in + (size_t)b * T;
    for (int i = threadIdx.x; i < T; i += blockDim.x) an[i] = row[i];
    __syncthreads();
    if (use_part) {
        if (threadIdx.x == 0) {
            float tot = 0.f;
            for (int i = 0; i < npart; ++i) tot += partials[b * npart + i];
            stot = tot;
            alpha_sum[b] = tot;
        }
    } else {
        float s = 0.f;
        for (int i = threadIdx.x; i < T; i += blockDim.x) s += an[i];
        int lane0 = threadIdx.x & 63;
        int w0 = threadIdx.x >> 6;
#pragma unroll
        for (int off = 32; off > 0; off >>= 1) s += __shfl_down(s, off, 64);
        if (lane0 == 0) sm[w0] = s;
        __syncthreads();
        if (threadIdx.x == 0) {
            float tot = 0.f;
            int nw = blockDim.x >> 6;
            for (int i = 0; i < nw; ++i) tot += sm[i];
            stot = tot;
            alpha_sum[b] = tot;
        }
    }
    __syncthreads();
    float ssum = stot;
    float yl = (float)ylens[b];
    for (int i = threadIdx.x; i < T; i += blockDim.x) an[i] = an[i] / ssum * yl;
    __syncthreads();
    if (threadIdx.x >= 64) return;
    int lane = threadIdx.x;
    int elen = elens[b];
    if (elen > T) elen = T;
    const int ylen = ylens[b];
    int* __restrict__ ft = fire_t + (size_t)b * Lp1;
    float* __restrict__ fa1 = fire_a1 + (size_t)b * Lp1;
    float* __restrict__ fa2 = fire_a2 + (size_t)b * Lp1;
    float accum = 0.f;
    int n = 0;
    bool done = false;
    for (int t0 = 0; t0 < elen && !done; t0 += 64) {
        int nv = elen - t0;
        if (nv > 64) nv = 64;
        float a = (lane < nv) ? an[t0 + lane] : 0.f;
        float P = a;
#pragma unroll
        for (int off = 1; off < 64; off <<= 1) {
            float tmp = __shfl_up(P, off, 64);
            if (lane >= off) P += tmp;
        }
        unsigned long long validmask = (nv == 64) ? ~0ull : ((1ull << nv) - 1ull);
        float base = accum;
        int start = 0;
        while (true) {
            bool cond = (base + P >= 0.9f);
            unsigned long long bal = __ballot(cond) & validmask;
            if (start > 0) bal &= (~0ull) << start;
            if (bal == 0) break;
            int u = __builtin_ctzll(bal);
            float Pu = __shfl(P, u, 64);
            float au = __shfl(a, u, 64);
            float accum_f = base + Pu;
            float ak1 = 1.f - accum_f;
            float ak2 = au - ak1;
            if (lane == 0) { ft[n] = t0 + u; fa1[n] = ak1; fa2[n] = ak2; }
            ++n;
            if (n >= ylen) { done = true; break; }
            base = ak2 - Pu;
            start = u + 1;
            if (start >= nv) break;
        }
        if (!done) {
            float Plast = __shfl(P, nv - 1, 64);
            accum = base + Plast;
        }
    }
    if (lane == 0) n_fired[b] = n;
}

__global__ void k_awfired(const float* __restrict__ eouts,
                          const float* __restrict__ alpha,
                          const float* __restrict__ alpha_sum,
                          const int* __restrict__ elens,
                          const int* __restrict__ ylens,
                          const int* __restrict__ n_fired,
                          const int* __restrict__ fire_t,
                          const float* __restrict__ fire_a1,
                          const float* __restrict__ fire_a2,
                          float* __restrict__ aws,
                          float* __restrict__ fired,
                          int T, int D, int L, int Lp1,
                          int AB, int tcpb, int DB) {
    if ((int)blockIdx.x < AB) {
        __shared__ int fts[MAXF];
        __shared__ float a1s[MAXF];
        __shared__ float a2s[MAXF];
        int b = blockIdx.x / tcpb;
        int tc = blockIdx.x % tcpb;
        int nf = n_fired[b];
        for (int i = threadIdx.x; i < nf; i += blockDim.x) {
            fts[i] = fire_t[(size_t)b * Lp1 + i];
            a1s[i] = fire_a1[(size_t)b * Lp1 + i];
            a2s[i] = fire_a2[(size_t)b * Lp1 + i];
        }
        __syncthreads();
        int t = tc * 256 + threadIdx.x;
        if (t >= T) return;
        int elen = elens[b];
        if (elen > T) elen = T;
        int ylen = ylens[b];
        bool active = (t < elen);
        int rowi = 0;
        bool isfire = false;
        float v1 = 0.f, v2 = 0.f;
        if (active) {
            int lo = 0, hi = nf;
            while (lo < hi) {
                int mid = (lo + hi) >> 1;
                if (fts[mid] < t) lo = mid + 1; else hi = mid;
            }
            rowi = lo;
            isfire = (rowi < nf && fts[rowi] == t);
            if (isfire) { v1 = a1s[rowi]; v2 = a2s[rowi]; }
            else if (rowi < ylen) v1 = alpha[(size_t)b * T + t] / alpha_sum[b] * (float)ylen;
            else active = false;
        }
        float* col = aws + (size_t)b * Lp1 * T + t;
        for (int r = 0; r < Lp1; ++r) {
            float v = 0.f;
            if (active) {
                if (r == rowi) v = v1;
                else if (isfire && r == rowi + 1) v = v2;
            }
            col[(size_t)r * T] = v;
        }
    } else {
        int idx = blockIdx.x - AB;
        int b = idx / (L * DB);
        int rem = idx % (L * DB);
        int n = rem / DB;
        int d = (rem % DB) * 256 + threadIdx.x;
        if (d >= D) return;
        int nf = n_fired[b];
        float* dst = fired + ((size_t)b * L + n) * D + d;
        if (n >= nf) { *dst = 0.f; return; }
        int t0 = (n == 0) ? 0 : fire_t[(size_t)b * Lp1 + n - 1];
        int t1 = fire_t[(size_t)b * Lp1 + n];
        float ak1 = fire_a1[(size_t)b * Lp1 + n];
        float ak2p = (n > 0) ? fire_a2[(size_t)b * Lp1 + n - 1] : 0.f;
        float ssum = alpha_sum[b];
        float yl = (float)ylens[b];
        const float* e = eouts + ((size_t)b * T + t0) * D + d;
        float accv = 0.f;
        for (int t = t0; t <= t1; ++t, e += D) {
            float wgt;
            if (t == t1) wgt = ak1;
            else if (t == t0 && n > 0) wgt = ak2p;
            else wgt = alpha[(size_t)b * T + t] / ssum * yl;
            accv += wgt * e[0];
        }
        *dst = accv;
    }
}

// ---------------- cooperative mega-kernel ----------------
// Static LDS 29952 B (<32 KiB so even a 64 KiB-pool occupancy calc gives
// 2 blocks/CU). ALL phases grid-stride; launched with grid clamped to the
// queried co-residency. Launch return code checked; fallback = kernels above.
struct MegaArgs {
    const float *eouts, *conv_w, *conv_b, *proj_w, *proj_b;
    const int *elens, *ylens;
    float *w_eff, *b_eff, *alpha_sum;
    int *n_fired, *fire_t;
    float *fire_a1, *fire_a2, *qbuf, *partials;
    float *fired, *alpha, *aws;
    int B, T, D, C, L, Lp1, tcb, BT;
};

__global__ __launch_bounds__(256, 2) void k_mega(MegaArgs a) {
    cg::grid_group gridg = cg::this_grid();
    __shared__ __align__(16) char smem[29952];
    const int lane = threadIdx.x & 63;

    // ---- phase 1: w_eff / b_eff (wave-task grid-stride) ----
    {
        const int KD = 11 * a.D;
        int gwave = (int)((blockIdx.x * 256 + threadIdx.x) >> 6);
        int nw = (int)gridDim.x * 4;
        for (int wv = gwave; wv <= KD; wv += nw) {
            float s = 0.f;
            if (wv < KD) {
                const float* row = a.conv_w + (size_t)wv * a.C;
                for (int c = lane * 4; c < a.C; c += 256) {
                    float4 v = *reinterpret_cast<const float4*>(row + c);
                    float4 w = *reinterpret_cast<const float4*>(a.proj_w + c);
                    s += v.x * w.x + v.y * w.y + v.z * w.z + v.w * w.w;
                }
            } else {
                for (int c = lane; c < a.C; c += 64) s += a.conv_b[c] * a.proj_w[c];
            }
#pragma unroll
            for (int off = 32; off > 0; off >>= 1) s += __shfl_down(s, off, 64);
            if (lane == 0) {
                if (wv < KD) a.w_eff[wv] = s;
                else         a.b_eff[0] = s + a.proj_b[0];
            }
        }
    }
    __threadfence();
    gridg.sync();

    // ---- phase 2: qdot, 64 rows x 64-float chunks (LDS 29952 B) ----
    {
        float* tile = (float*)smem;          // 64*68 floats
        float* part = tile + 64 * 68;        // 64*49 floats
        const int sw = threadIdx.x >> 6;     // wave id (w_eff written in-kernel -> vector loads regardless)
        const int ntile = a.BT >> 6;
        for (int tl = blockIdx.x; tl < ntile; tl += gridDim.x) {
            const int u0 = tl << 6;
            float acc[11];
#pragma unroll
            for (int k = 0; k < 11; ++k) acc[k] = 0.f;
            for (int c = 0; c < 8; ++c) {
                __syncthreads();
#pragma unroll
                for (int it = 0; it < 4; ++it) {
                    int idx = it * 256 + threadIdx.x;
                    int r = idx >> 4, j4 = idx & 15;
                    float4 v = *reinterpret_cast<const float4*>(
                        a.eouts + (size_t)(u0 + r) * 512 + c * 64 + j4 * 4);
                    *reinterpret_cast<float4*>(&tile[r * 68 + j4 * 4]) = v;
                }
                __syncthreads();
#pragma unroll
                for (int j4 = 0; j4 < 4; ++j4) {
                    float4 av = *reinterpret_cast<const float4*>(&tile[lane * 68 + sw * 16 + j4 * 4]);
                    int dg = c * 64 + sw * 16 + j4 * 4;
#pragma unroll
                    for (int k = 0; k < 11; ++k) {
                        float4 wv = *reinterpret_cast<const float4*>(a.w_eff + k * 512 + dg);
                        acc[k] += av.x * wv.x + av.y * wv.y + av.z * wv.z + av.w * wv.w;
                    }
                }
            }
            __syncthreads();
#pragma unroll
            for (int k = 0; k < 11; ++k) part[lane * 49 + sw * 12 + k] = acc[k];
            __syncthreads();
            if (threadIdx.x < 64) {
                int r = threadIdx.x;
                const float* p = &part[r * 49];
                float o[12];
#pragma unroll
                for (int k = 0; k < 11; ++k)
                    o[k] = (p[k] + p[12 + k]) + (p[24 + k] + p[36 + k]);
                o[11] = 0.f;
                float4* dst = reinterpret_cast<float4*>(a.qbuf + (size_t)(u0 + r) * 12);
                dst[0] = make_float4(o[0], o[1], o[2], o[3]);
                dst[1] = make_float4(o[4], o[5], o[6], o[7]);
                dst[2] = make_float4(o[8], o[9], o[10], o[11]);
            }
        }
    }
    __threadfence();
    gridg.sync();

    // ---- phase 3: sigma + block partial sums ----
    for (int bx = blockIdx.x; bx < a.B * a.tcb; bx += gridDim.x) {
        float* qs = (float*)smem;        // 266*12
        float* psm = qs + 266 * 12;      // 4
        int b = bx / a.tcb, tc = bx % a.tcb;
        int t0 = tc * 256;
        const float* qb = a.qbuf + (size_t)b * a.T * 12;
        const int base = (t0 - 5) * 12;
        const int lim = a.T * 12;
        __syncthreads();
        for (int i = threadIdx.x; i < 266 * 12; i += 256) {
            int gi = base + i;
            qs[i] = (gi >= 0 && gi < lim) ? qb[gi] : 0.f;
        }
        __syncthreads();
        int t = t0 + threadIdx.x;
        float sacc = a.b_eff[0];
#pragma unroll
        for (int k = 0; k < 11; ++k) sacc += qs[(threadIdx.x + k) * 12 + k];
        float al = 1.f / (1.f + expf(-sacc));
        a.alpha[(size_t)b * a.T + t] = al;
        float s = al;
        int w = threadIdx.x >> 6;
#pragma unroll
        for (int off = 32; off > 0; off >>= 1) s += __shfl_down(s, off, 64);
        if (lane == 0) psm[w] = s;
        __syncthreads();
        if (threadIdx.x == 0) {
            float tot = 0.f;
            for (int i = 0; i < 4; ++i) tot += psm[i];
            a.partials[bx] = tot;
        }
    }
    __threadfence();
    gridg.sync();

    // ---- phase 4: rowsum-from-partials + normalize + fire scan ----
    for (int b = blockIdx.x; b < a.B; b += gridDim.x) {
        float* an = (float*)smem;    // T floats
        float* ssh = an + a.T;       // 1 float
        const float* row = a.alpha + (size_t)b * a.T;
        __syncthreads();
        for (int i = threadIdx.x; i < a.T; i += 256) an[i] = row[i];
        if (threadIdx.x == 0) {
            float tot = 0.f;
            for (int i = 0; i < a.tcb; ++i) tot += a.partials[b * a.tcb + i];
            ssh[0] = tot;
            a.alpha_sum[b] = tot;
        }
        __syncthreads();
        float ssum = ssh[0];
        float yl = (float)a.ylens[b];
        for (int i = threadIdx.x; i < a.T; i += 256) an[i] = an[i] / ssum * yl;
        __syncthreads();
        if (threadIdx.x < 64) {
            int elen = a.elens[b];
            if (elen > a.T) elen = a.T;
            const int ylen = a.ylens[b];
            int* ft = a.fire_t + (size_t)b * a.Lp1;
            float* fa1 = a.fire_a1 + (size_t)b * a.Lp1;
            float* fa2 = a.fire_a2 + (size_t)b * a.Lp1;
            float accum = 0.f;
            int n = 0;
            bool done = false;
            for (int t0 = 0; t0 < elen && !done; t0 += 64) {
                int nv = elen - t0;
                if (nv > 64) nv = 64;
                float av = (lane < nv) ? an[t0 + lane] : 0.f;
                float P = av;
#pragma unroll
                for (int off = 1; off < 64; off <<= 1) {
                    float tmp = __shfl_up(P, off, 64);
                    if (lane >= off) P += tmp;
                }
                unsigned long long validmask = (nv == 64) ? ~0ull : ((1ull << nv) - 1ull);
                float base = accum;
                int start = 0;
                while (true) {
                    bool cond = (base + P >= 0.9f);
                    unsigned long long bal = __ballot(cond) & validmask;
                    if (start > 0) bal &= (~0ull) << start;
                    if (bal == 0) break;
                    int u = __builtin_ctzll(bal);
                    float Pu = __shfl(P, u, 64);
                    float au = __shfl(av, u, 64);
                    float accum_f = base + Pu;
                    float ak1 = 1.f - accum_f;
                    float ak2 = au - ak1;
                    if (lane == 0) { ft[n] = t0 + u; fa1[n] = ak1; fa2[n] = ak2; }
                    ++n;
                    if (n >= ylen) { done = true; break; }
                    base = ak2 - Pu;
                    start = u + 1;
                    if (start >= nv) break;
                }
                if (!done) {
                    float Plast = __shfl(P, nv - 1, 64);
                    accum = base + Plast;
                }
            }
            if (lane == 0) a.n_fired[b] = n;
        }
    }
    __threadfence();
    gridg.sync();

    // ---- phase 5: aws writer + fired (grid-stride tasks) ----
    {
        const int AB = a.B * a.tcb;
        const int DB = (a.D + 255) / 256;
        const int total = AB + a.B * a.L * DB;
        int* fts = (int*)smem;
        float* a1s = (float*)(fts + MAXF);
        float* a2s = a1s + MAXF;
        for (int task = blockIdx.x; task < total; task += gridDim.x) {
            if (task < AB) {
                int b = task / a.tcb;
                int tc = task % a.tcb;
                int nf = a.n_fired[b];
                __syncthreads();
                for (int i = threadIdx.x; i < nf; i += 256) {
                    fts[i] = a.fire_t[(size_t)b * a.Lp1 + i];
                    a1s[i] = a.fire_a1[(size_t)b * a.Lp1 + i];
                    a2s[i] = a.fire_a2[(size_t)b * a.Lp1 + i];
                }
                __syncthreads();
                int t = tc * 256 + threadIdx.x;
                if (t < a.T) {
                    int elen = a.elens[b];
                    if (elen > a.T) elen = a.T;
                    int ylen = a.ylens[b];
                    bool active = (t < elen);
                    int rowi = 0;
                    bool isfire = false;
                    float v1 = 0.f, v2 = 0.f;
                    if (active) {
                        int lo = 0, hi = nf;
                        while (lo < hi) {
                            int mid = (lo + hi) >> 1;
                            if (fts[mid] < t) lo = mid + 1; else hi = mid;
                        }
                        rowi = lo;
                        isfire = (rowi < nf && fts[rowi] == t);
                        if (isfire) { v1 = a1s[rowi]; v2 = a2s[rowi]; }
                        else if (rowi < ylen)
                            v1 = a.alpha[(size_t)b * a.T + t] / a.alpha_sum[b] * (float)ylen;
                        else active = false;
                    }
                    float* col = a.aws + (size_t)b * a.Lp1 * a.T + t;
                    for (int r = 0; r < a.Lp1; ++r) {
                        float v = 0.f;
                        if (active) {
                            if (r == rowi) v = v1;
                            else if (isfire && r == rowi + 1) v = v2;
                        }
                        col[(size_t)r * a.T] = v;
                    }
                }
            } else {
                int idx = task - AB;
                int b = idx / (a.L * DB);
                int rem = idx % (a.L * DB);
                int n = rem / DB;
                int d = (rem % DB) * 256 + threadIdx.x;
                if (d < a.D) {
                    int nf = a.n_fired[b];
                    float* dst = a.fired + ((size_t)b * a.L + n) * a.D + d;
                    if (n >= nf) { *dst = 0.f; }
                    else {
                        int t0 = (n == 0) ? 0 : a.fire_t[(size_t)b * a.Lp1 + n - 1];
                        int t1 = a.fire_t[(size_t)b * a.Lp1 + n];
                        float ak1 = a.fire_a1[(size_t)b * a.Lp1 + n];
                        float ak2p = (n > 0) ? a.fire_a2[(size_t)b * a.Lp1 + n - 1] : 0.f;
                        float ssum = a.alpha_sum[b];
                        float yl = (float)a.ylens[b];
                        const float* e = a.eouts + ((size_t)b * a.T + t0) * a.D + d;
                        float accv = 0.f;
                        for (int t = t0; t <= t1; ++t, e += a.D) {
                            float wgt;
                            if (t == t1) wgt = ak1;
                            else if (t == t0 && n > 0) wgt = ak2p;
                            else wgt = a.alpha[(size_t)b * a.T + t] / ssum * yl;
                            accv += wgt * e[0];
                        }
                        *dst = accv;
                    }
                }
            }
        }
    }
}

extern "C" void kernel_launch(void* const* d_in, const int* in_sizes, int n_in,
                              void* d_out, int out_size, void* d_ws, size_t ws_size,
                              hipStream_t stream) {
    const float* eouts  = (const float*)d_in[0];
    const float* conv_w = (const float*)d_in[1];
    const float* conv_b = (const float*)d_in[2];
    const float* proj_w = (const float*)d_in[3];
    const float* proj_b = (const float*)d_in[4];
    const int*   elens  = (const int*)d_in[5];
    const int*   ylens  = (const int*)d_in[6];

    const int B = in_sizes[5];
    const int C = in_sizes[2];
    const int W = 2 * KHALF + 1;
    const int D = in_sizes[1] / (W * C);
    const int T = in_sizes[0] / (B * D);
    const int L = (out_size - 2 * B * T) / (B * (D + T));
    const int Lp1 = L + 1;
    const int BT = B * T;
    const int tcb = (T + 255) / 256;

    float* out   = (float*)d_out;
    float* fired = out;                      // [B, L, D]
    float* alpha = out + (size_t)B * L * D;  // [B, T]
    float* aws   = alpha + (size_t)B * T;    // [B, 1, Lp1, T]

    char*  ws        = (char*)d_ws;
    float* w_eff     = (float*)ws;                              // W*D floats
    float* b_eff     = (float*)(ws + (size_t)W * D * 4);        // 1 float (+pad)
    float* alpha_sum = b_eff + 16;                              // B floats
    int*   n_fired   = (int*)(alpha_sum + B + 16);              // B ints
    int*   fire_t    = n_fired + B + 16;                        // B*Lp1 ints
    float* fire_a1   = (float*)(fire_t + (size_t)B * Lp1 + 16); // B*Lp1 floats
    float* fire_a2   = fire_a1 + (size_t)B * Lp1 + 16;          // B*Lp1 floats
    float* qbuf      = fire_a2 + (size_t)B * Lp1 + 16;          // BT*12 floats
    float* partials  = qbuf + (size_t)BT * 12 + 16;             // B*tcb floats
    size_t ws_need   = (size_t)((char*)(partials + (size_t)B * tcb + 16) - ws);

    const bool fast = (ws_size >= ws_need) && (D == 512) && (C == 512) &&
                      (BT % 64 == 0) && (T % 256 == 0) && (T <= 7424) &&
                      (Lp1 <= MAXF);

    bool coop_done = false;
    if (fast) {
        int dev = 0, nCU = 0, coopAttr = 0, occ = 0;
        hipGetDevice(&dev);
        hipDeviceGetAttribute(&nCU, hipDeviceAttributeMultiprocessorCount, dev);
        hipDeviceGetAttribute(&coopAttr, hipDeviceAttributeCooperativeLaunch, dev);
        hipOccupancyMaxActiveBlocksPerMultiprocessor(&occ, (const void*)k_mega, 256, 0);
        int maxBlk = occ * nCU;
        int nblk = BT / 64;
        if (nblk > maxBlk) nblk = maxBlk;
        if (coopAttr && nblk >= B && nblk >= 64) {
            MegaArgs a = { eouts, conv_w, conv_b, proj_w, proj_b, elens, ylens,
                           w_eff, b_eff, alpha_sum, n_fired, fire_t,
                           fire_a1, fire_a2, qbuf, partials,
                           fired, alpha, aws,
                           B, T, D, C, L, Lp1, tcb, BT };
            void* kargs[] = { (void*)&a };
            hipError_t e = hipLaunchCooperativeKernel((const void*)k_mega, dim3(nblk),
                                                      dim3(256), kargs, 0, stream);
            if (e == hipSuccess) coop_done = true;
            else (void)hipGetLastError();  // clear sticky error, fall through
        }
    }

    if (!coop_done) {
        const int KD = W * D;
        {
            long long threads = (long long)(KD + 1) * 64;
            int blocks = (int)((threads + 255) / 256);
            k_weff<<<blocks, 256, 0, stream>>>(conv_w, conv_b, proj_w, proj_b,
                                               w_eff, b_eff, KD, C);
        }
        if (fast) {
            k_qdot<<<BT / 64, 256, 0, stream>>>(eouts, w_eff, qbuf, BT);
            k_sigpart<<<B * tcb, 256, 0, stream>>>(qbuf, b_eff, alpha, partials, T, tcb);
        } else {
            long long threads = (long long)BT * 64;
            int blocks = (int)((threads + 255) / 256);
            k_alpha<<<blocks, 256, 0, stream>>>(eouts, w_eff, b_eff, alpha, B, T, D);
        }
        k_chain<<<B, 256, T * sizeof(float), stream>>>(
            alpha, fast ? 1 : 0, partials, tcb,
            elens, ylens, alpha_sum,
            n_fired, fire_t, fire_a1, fire_a2, T, Lp1);
        {
            int tcpb = (T + 255) / 256;
            int AB = B * tcpb;
            int DB = (D + 255) / 256;
            int FB = B * L * DB;
            k_awfired<<<AB + FB, 256, 0, stream>>>(eouts, alpha, alpha_sum,
                                                   elens, ylens, n_fired,
                                                   fire_t, fire_a1, fire_a2,
                                                   aws, fired, T, D, L, Lp1,
                                                   AB, tcpb, DB);
        }
    }
}

// Round 10
// 187.392 us; speedup vs baseline: 2.6974x; 2.6974x over previous
//
#include <hip/hip_runtime.h>
#include <math.h>

#define KHALF 5
#define MAXF 256  // max fire count per batch (Lp1 <= 128 here)

// K1: effective conv->proj weights: w_eff[k*D+d] = sum_c conv_w[k,d,c]*proj_w[c]
// One WAVE per output element; extra wave computes b_eff.
__global__ void k_weff(const float* __restrict__ conv_w, const float* __restrict__ conv_b,
                       const float* __restrict__ proj_w, const float* __restrict__ proj_b,
                       float* __restrict__ w_eff, float* __restrict__ b_eff,
                       int KD, int C) {
    int gid = blockIdx.x * blockDim.x + threadIdx.x;
    int wave = gid >> 6;
    int lane = gid & 63;
    if (wave > KD) return;
    float s = 0.f;
    if (wave < KD) {
        const float* row = conv_w + (size_t)wave * C;
        for (int c = lane * 4; c < C; c += 256) {
            float4 v = *reinterpret_cast<const float4*>(row + c);
            float4 w = *reinterpret_cast<const float4*>(proj_w + c);
            s += v.x * w.x + v.y * w.y + v.z * w.z + v.w * w.w;
        }
    } else {
        for (int c = lane; c < C; c += 64) s += conv_b[c] * proj_w[c];
    }
#pragma unroll
    for (int off = 32; off > 0; off >>= 1) s += __shfl_down(s, off, 64);
    if (lane == 0) {
        if (wave < KD) w_eff[wave] = s;
        else           b_eff[0] = s + proj_b[0];
    }
}

// K2a v4: q[u][k] = dot(eouts[u,:], w_eff[k,:]), k=0..10. D==512 specialized.
// Block = 64 rows, 256 threads (wave sw owns the 16-d sub-slice of each
// 64-d chunk). Same chunking/FMA order as R9-mega phase 2 (correctness-
// verified end-to-end). New: per-chunk w-slab staged into LDS (wls, 2.8 KB)
// and read via all-lanes-same-address broadcast ds_read_b128 — avoids the
// s_load scalar-cache thrash of the global-w variant (w_eff 22.5 KB > sKcache).
__global__ __launch_bounds__(256) void k_qdot(const float* __restrict__ eouts,
                                              const float* __restrict__ w_eff,
                                              float* __restrict__ q, int BT) {
    __shared__ float tile[64 * 68];   // 17408 B
    __shared__ float wls[11 * 68];    //  2992 B
    __shared__ float part[64 * 49];   // 12544 B (stride 49: odd, spreads banks)
    const int u0 = blockIdx.x * 64;
    const int lane = threadIdx.x & 63;
    const int sw = threadIdx.x >> 6;  // 0..3
    float acc[11];
#pragma unroll
    for (int k = 0; k < 11; ++k) acc[k] = 0.f;
    for (int c = 0; c < 8; ++c) {
        __syncthreads();  // WAR on tile/wls from previous chunk's readers
        // stage eouts tile: 64 rows x 64 floats (coalesced global, LDS stride 68)
#pragma unroll
        for (int it = 0; it < 4; ++it) {
            int idx = it * 256 + threadIdx.x;
            int r = idx >> 4, j4 = idx & 15;
            float4 v = *reinterpret_cast<const float4*>(
                eouts + (size_t)(u0 + r) * 512 + c * 64 + j4 * 4);
            *reinterpret_cast<float4*>(&tile[r * 68 + j4 * 4]) = v;
        }
        // stage w slab: 11 k x 64 floats
        if (threadIdx.x < 176) {
            int k = threadIdx.x >> 4, sl = threadIdx.x & 15;
            float4 wv = *reinterpret_cast<const float4*>(
                w_eff + k * 512 + c * 64 + sl * 4);
            *reinterpret_cast<float4*>(&wls[k * 68 + sl * 4]) = wv;
        }
        __syncthreads();
#pragma unroll
        for (int j4 = 0; j4 < 4; ++j4) {
            float4 av = *reinterpret_cast<const float4*>(&tile[lane * 68 + sw * 16 + j4 * 4]);
            int dl = sw * 16 + j4 * 4;
#pragma unroll
            for (int k = 0; k < 11; ++k) {
                float4 wv = *reinterpret_cast<const float4*>(&wls[k * 68 + dl]);  // broadcast
                acc[k] += av.x * wv.x + av.y * wv.y + av.z * wv.z + av.w * wv.w;
            }
        }
    }
    __syncthreads();
#pragma unroll
    for (int k = 0; k < 11; ++k) part[lane * 49 + sw * 12 + k] = acc[k];
    __syncthreads();
    if (threadIdx.x < 64) {
        int r = threadIdx.x;
        const float* p = &part[r * 49];
        float o[12];
#pragma unroll
        for (int k = 0; k < 11; ++k)
            o[k] = (p[k] + p[12 + k]) + (p[24 + k] + p[36 + k]);
        o[11] = 0.f;
        float4* dst = reinterpret_cast<float4*>(q + (size_t)(u0 + r) * 12);
        dst[0] = make_float4(o[0], o[1], o[2], o[3]);
        dst[1] = make_float4(o[4], o[5], o[6], o[7]);
        dst[2] = make_float4(o[8], o[9], o[10], o[11]);
    }
}

// K2b: alpha[b,t] = sigmoid(sum_k q[t-5+k][k] + bias) + per-block partial sums.
__global__ __launch_bounds__(256) void k_sigpart(const float* __restrict__ q,
                                                 const float* __restrict__ b_eff,
                                                 float* __restrict__ alpha,
                                                 float* __restrict__ partials,
                                                 int T, int tcb) {
    __shared__ float qs[266 * 12];
    __shared__ float psm[4];
    int bx = blockIdx.x;
    int b = bx / tcb, tc = bx % tcb;
    int t0 = tc * 256;
    const float* qb = q + (size_t)b * T * 12;
    const int base = (t0 - 5) * 12;
    const int lim = T * 12;
    for (int i = threadIdx.x; i < 266 * 12; i += 256) {
        int gi = base + i;
        qs[i] = (gi >= 0 && gi < lim) ? qb[gi] : 0.f;
    }
    __syncthreads();
    int t = t0 + threadIdx.x;
    float sacc = b_eff[0];
#pragma unroll
    for (int k = 0; k < 11; ++k) sacc += qs[(threadIdx.x + k) * 12 + k];
    float al = 1.f / (1.f + expf(-sacc));
    alpha[(size_t)b * T + t] = al;
    float s = al;
    int lane = threadIdx.x & 63;
    int w = threadIdx.x >> 6;
#pragma unroll
    for (int off = 32; off > 0; off >>= 1) s += __shfl_down(s, off, 64);
    if (lane == 0) psm[w] = s;
    __syncthreads();
    if (threadIdx.x == 0) {
        float tot = 0.f;
        for (int i = 0; i < 4; ++i) tot += psm[i];
        partials[bx] = tot;
    }
}

// K2 fallback (generic D): windowed dot, one wave per (b,t), writes alpha.
__global__ void k_alpha(const float* __restrict__ eouts,
                        const float* __restrict__ w_eff,
                        const float* __restrict__ b_eff,
                        float* __restrict__ alpha,
                        int B, int T, int D) {
    const int W = 2 * KHALF + 1;
    int gid = blockIdx.x * blockDim.x + threadIdx.x;
    int wave = gid >> 6;
    int lane = gid & 63;
    if (wave >= B * T) return;
    int b = wave / T;
    int t = wave - b * T;
    int WD = W * D;
    int t0 = t - KHALF;
    float s = 0.f;
    if (t0 >= 0 && t0 + W <= T) {
        const float* base = eouts + ((size_t)b * T + t0) * D;
        for (int j = lane * 4; j < WD; j += 256) {
            float4 v = *reinterpret_cast<const float4*>(base + j);
            float4 w = *reinterpret_cast<const float4*>(w_eff + j);
            s += v.x * w.x + v.y * w.y + v.z * w.z + v.w * w.w;
        }
    } else {
        const float* base = eouts + (size_t)b * T * D;
        for (int j = lane; j < WD; j += 64) {
            int tt = t0 + j / D;
            if (tt >= 0 && tt < T) {
                int d = j - (j / D) * D;
                s += base[(size_t)tt * D + d] * w_eff[j];
            }
        }
    }
#pragma unroll
    for (int off = 32; off > 0; off >>= 1) s += __shfl_down(s, off, 64);
    if (lane == 0) {
        float logit = s + b_eff[0];
        alpha[(size_t)b * T + t] = 1.f / (1.f + expf(-logit));
    }
}

// K3: rowsum (from partials in fast path) + normalize + fire scan.
__global__ void k_chain(const float* __restrict__ alpha_in,
                        int use_part,
                        const float* __restrict__ partials, int npart,
                        const int* __restrict__ elens,
                        const int* __restrict__ ylens,
                        float* __restrict__ alpha_sum,
                        int* __restrict__ n_fired,
                        int* __restrict__ fire_t,
                        float* __restrict__ fire_a1,
                        float* __restrict__ fire_a2,
                        int T, int Lp1) {
    extern __shared__ float an[];
    __shared__ float sm[16];
    __shared__ float stot;
    int b = blockIdx.x;
    const float* row = alpha_in + (size_t)b * T;
    for (int i = threadIdx.x; i < T; i += blockDim.x) an[i] = row[i];
    __syncthreads();
    if (use_part) {
        if (threadIdx.x == 0) {
            float tot = 0.f;
            for (int i = 0; i < npart; ++i) tot += partials[b * npart + i];
            stot = tot;
            alpha_sum[b] = tot;
        }
    } else {
        float s = 0.f;
        for (int i = threadIdx.x; i < T; i += blockDim.x) s += an[i];
        int lane0 = threadIdx.x & 63;
        int w0 = threadIdx.x >> 6;
#pragma unroll
        for (int off = 32; off > 0; off >>= 1) s += __shfl_down(s, off, 64);
        if (lane0 == 0) sm[w0] = s;
        __syncthreads();
        if (threadIdx.x == 0) {
            float tot = 0.f;
            int nw = blockDim.x >> 6;
            for (int i = 0; i < nw; ++i) tot += sm[i];
            stot = tot;
            alpha_sum[b] = tot;
        }
    }
    __syncthreads();
    float ssum = stot;
    float yl = (float)ylens[b];
    for (int i = threadIdx.x; i < T; i += blockDim.x) an[i] = an[i] / ssum * yl;
    __syncthreads();
    if (threadIdx.x >= 64) return;
    int lane = threadIdx.x;
    int elen = elens[b];
    if (elen > T) elen = T;
    const int ylen = ylens[b];
    int* __restrict__ ft = fire_t + (size_t)b * Lp1;
    float* __restrict__ fa1 = fire_a1 + (size_t)b * Lp1;
    float* __restrict__ fa2 = fire_a2 + (size_t)b * Lp1;
    float accum = 0.f;
    int n = 0;
    bool done = false;
    for (int t0 = 0; t0 < elen && !done; t0 += 64) {
        int nv = elen - t0;
        if (nv > 64) nv = 64;
        float a = (lane < nv) ? an[t0 + lane] : 0.f;
        float P = a;
#pragma unroll
        for (int off = 1; off < 64; off <<= 1) {
            float tmp = __shfl_up(P, off, 64);
            if (lane >= off) P += tmp;
        }
        unsigned long long validmask = (nv == 64) ? ~0ull : ((1ull << nv) - 1ull);
        float base = accum;
        int start = 0;
        while (true) {
            bool cond = (base + P >= 0.9f);
            unsigned long long bal = __ballot(cond) & validmask;
            if (start > 0) bal &= (~0ull) << start;
            if (bal == 0) break;
            int u = __builtin_ctzll(bal);
            float Pu = __shfl(P, u, 64);
            float au = __shfl(a, u, 64);
            float accum_f = base + Pu;
            float ak1 = 1.f - accum_f;
            float ak2 = au - ak1;
            if (lane == 0) { ft[n] = t0 + u; fa1[n] = ak1; fa2[n] = ak2; }
            ++n;
            if (n >= ylen) { done = true; break; }
            base = ak2 - Pu;
            start = u + 1;
            if (start >= nv) break;
        }
        if (!done) {
            float Plast = __shfl(P, nv - 1, 64);
            accum = base + Plast;
        }
    }
    if (lane == 0) n_fired[b] = n;
}

// K4: fused aws writer (incl. background zeros) + fired (incl. zero tail rows).
__global__ void k_awfired(const float* __restrict__ eouts,
                          const float* __restrict__ alpha,
                          const float* __restrict__ alpha_sum,
                          const int* __restrict__ elens,
                          const int* __restrict__ ylens,
                          const int* __restrict__ n_fired,
                          const int* __restrict__ fire_t,
                          const float* __restrict__ fire_a1,
                          const float* __restrict__ fire_a2,
                          float* __restrict__ aws,
                          float* __restrict__ fired,
                          int T, int D, int L, int Lp1,
                          int AB, int tcpb, int DB) {
    if ((int)blockIdx.x < AB) {
        __shared__ int fts[MAXF];
        __shared__ float a1s[MAXF];
        __shared__ float a2s[MAXF];
        int b = blockIdx.x / tcpb;
        int tc = blockIdx.x % tcpb;
        int nf = n_fired[b];
        for (int i = threadIdx.x; i < nf; i += blockDim.x) {
            fts[i] = fire_t[(size_t)b * Lp1 + i];
            a1s[i] = fire_a1[(size_t)b * Lp1 + i];
            a2s[i] = fire_a2[(size_t)b * Lp1 + i];
        }
        __syncthreads();
        int t = tc * 256 + threadIdx.x;
        if (t >= T) return;
        int elen = elens[b];
        if (elen > T) elen = T;
        int ylen = ylens[b];
        bool active = (t < elen);
        int rowi = 0;
        bool isfire = false;
        float v1 = 0.f, v2 = 0.f;
        if (active) {
            int lo = 0, hi = nf;
            while (lo < hi) {
                int mid = (lo + hi) >> 1;
                if (fts[mid] < t) lo = mid + 1; else hi = mid;
            }
            rowi = lo;
            isfire = (rowi < nf && fts[rowi] == t);
            if (isfire) { v1 = a1s[rowi]; v2 = a2s[rowi]; }
            else if (rowi < ylen) v1 = alpha[(size_t)b * T + t] / alpha_sum[b] * (float)ylen;
            else active = false;
        }
        float* col = aws + (size_t)b * Lp1 * T + t;
        for (int r = 0; r < Lp1; ++r) {
            float v = 0.f;
            if (active) {
                if (r == rowi) v = v1;
                else if (isfire && r == rowi + 1) v = v2;
            }
            col[(size_t)r * T] = v;
        }
    } else {
        int idx = blockIdx.x - AB;
        int b = idx / (L * DB);
        int rem = idx % (L * DB);
        int n = rem / DB;
        int d = (rem % DB) * 256 + threadIdx.x;
        if (d >= D) return;
        int nf = n_fired[b];
        float* dst = fired + ((size_t)b * L + n) * D + d;
        if (n >= nf) { *dst = 0.f; return; }
        int t0 = (n == 0) ? 0 : fire_t[(size_t)b * Lp1 + n - 1];
        int t1 = fire_t[(size_t)b * Lp1 + n];
        float ak1 = fire_a1[(size_t)b * Lp1 + n];
        float ak2p = (n > 0) ? fire_a2[(size_t)b * Lp1 + n - 1] : 0.f;
        float ssum = alpha_sum[b];
        float yl = (float)ylens[b];
        const float* e = eouts + ((size_t)b * T + t0) * D + d;
        float accv = 0.f;
        for (int t = t0; t <= t1; ++t, e += D) {
            float wgt;
            if (t == t1) wgt = ak1;
            else if (t == t0 && n > 0) wgt = ak2p;
            else wgt = alpha[(size_t)b * T + t] / ssum * yl;
            accv += wgt * e[0];
        }
        *dst = accv;
    }
}

extern "C" void kernel_launch(void* const* d_in, const int* in_sizes, int n_in,
                              void* d_out, int out_size, void* d_ws, size_t ws_size,
                              hipStream_t stream) {
    const float* eouts  = (const float*)d_in[0];
    const float* conv_w = (const float*)d_in[1];
    const float* conv_b = (const float*)d_in[2];
    const float* proj_w = (const float*)d_in[3];
    const float* proj_b = (const float*)d_in[4];
    const int*   elens  = (const int*)d_in[5];
    const int*   ylens  = (const int*)d_in[6];

    const int B = in_sizes[5];
    const int C = in_sizes[2];
    const int W = 2 * KHALF + 1;
    const int D = in_sizes[1] / (W * C);
    const int T = in_sizes[0] / (B * D);
    const int L = (out_size - 2 * B * T) / (B * (D + T));
    const int Lp1 = L + 1;
    const int BT = B * T;
    const int tcb = (T + 255) / 256;

    float* out   = (float*)d_out;
    float* fired = out;                      // [B, L, D]
    float* alpha = out + (size_t)B * L * D;  // [B, T]
    float* aws   = alpha + (size_t)B * T;    // [B, 1, Lp1, T]

    char*  ws        = (char*)d_ws;
    float* w_eff     = (float*)ws;                              // W*D floats
    float* b_eff     = (float*)(ws + (size_t)W * D * 4);        // 1 float (+pad)
    float* alpha_sum = b_eff + 16;                              // B floats
    int*   n_fired   = (int*)(alpha_sum + B + 16);              // B ints
    int*   fire_t    = n_fired + B + 16;                        // B*Lp1 ints
    float* fire_a1   = (float*)(fire_t + (size_t)B * Lp1 + 16); // B*Lp1 floats
    float* fire_a2   = fire_a1 + (size_t)B * Lp1 + 16;          // B*Lp1 floats
    float* qbuf      = fire_a2 + (size_t)B * Lp1 + 16;          // BT*12 floats
    float* partials  = qbuf + (size_t)BT * 12 + 16;             // B*tcb floats
    size_t ws_need   = (size_t)((char*)(partials + (size_t)B * tcb + 16) - ws);

    const int KD = W * D;
    {
        long long threads = (long long)(KD + 1) * 64;
        int blocks = (int)((threads + 255) / 256);
        k_weff<<<blocks, 256, 0, stream>>>(conv_w, conv_b, proj_w, proj_b,
                                           w_eff, b_eff, KD, C);
    }

    const bool fast = (ws_size >= ws_need) && (D == 512) && (C == 512) &&
                      (BT % 64 == 0) && (T % 256 == 0) && (T <= 16384) &&
                      (Lp1 <= MAXF);
    if (fast) {
        k_qdot<<<BT / 64, 256, 0, stream>>>(eouts, w_eff, qbuf, BT);
        k_sigpart<<<B * tcb, 256, 0, stream>>>(qbuf, b_eff, alpha, partials, T, tcb);
    } else {
        long long threads = (long long)BT * 64;
        int blocks = (int)((threads + 255) / 256);
        k_alpha<<<blocks, 256, 0, stream>>>(eouts, w_eff, b_eff, alpha, B, T, D);
    }

    k_chain<<<B, 256, T * sizeof(float), stream>>>(
        alpha, fast ? 1 : 0, partials, tcb,
        elens, ylens, alpha_sum,
        n_fired, fire_t, fire_a1, fire_a2, T, Lp1);

    {
        int tcpb = (T + 255) / 256;
        int AB = B * tcpb;
        int DB = (D + 255) / 256;
        int FB = B * L * DB;
        k_awfired<<<AB + FB, 256, 0, stream>>>(eouts, alpha, alpha_sum,
                                               elens, ylens, n_fired,
                                               fire_t, fire_a1, fire_a2,
                                               aws, fired, T, D, L, Lp1,
                                               AB, tcpb, DB);
    }
}